// Round 7
// baseline (479.756 us; speedup 1.0000x reference)
//
#include <hip/hip_runtime.h>
#include <cstdint>
#include <cstddef>

constexpr int kN = 50000;
constexpr float kSlope = 0.2f;
constexpr float kBnEps = 1e-5f;

static inline int ceil_div(int a, int b) { return (a + b - 1) / b; }

typedef __attribute__((ext_vector_type(8))) short bf16x8;
typedef __attribute__((ext_vector_type(8))) unsigned short ushortx8;
typedef __attribute__((ext_vector_type(4))) float f32x4;

__device__ inline unsigned short f2bf(float f) {
  unsigned int u = __float_as_uint(f);
  u = (u + 0x7FFFu + ((u >> 16) & 1u)) >> 16;
  return (unsigned short)u;
}
__device__ inline float bf2f(unsigned short h) {
  return __uint_as_float(((unsigned int)h) << 16);
}

// ---------------- CSR build ----------------

__global__ void k_degree(const int* __restrict__ dst, int* __restrict__ deg, int E) {
  int e = blockIdx.x * blockDim.x + threadIdx.x;
  if (e < E) atomicAdd(&deg[dst[e]], 1);
}

__global__ void k_scan1(const int* __restrict__ deg, int* __restrict__ rp,
                        int* __restrict__ bsum, int n) {
  __shared__ int sm[256];
  int i = blockIdx.x * 256 + threadIdx.x;
  int v = (i < n) ? deg[i] : 0;
  sm[threadIdx.x] = v;
  __syncthreads();
  for (int off = 1; off < 256; off <<= 1) {
    int t = (threadIdx.x >= off) ? sm[threadIdx.x - off] : 0;
    __syncthreads();
    sm[threadIdx.x] += t;
    __syncthreads();
  }
  if (i < n) rp[i + 1] = sm[threadIdx.x];
  if (threadIdx.x == 255) bsum[blockIdx.x] = sm[255];
}

__global__ void k_scan2(int* bsum, int nb) {
  __shared__ int sm[256];
  int v = (threadIdx.x < nb) ? bsum[threadIdx.x] : 0;
  sm[threadIdx.x] = v;
  __syncthreads();
  for (int off = 1; off < 256; off <<= 1) {
    int t = (threadIdx.x >= off) ? sm[threadIdx.x - off] : 0;
    __syncthreads();
    sm[threadIdx.x] += t;
    __syncthreads();
  }
  if (threadIdx.x < nb) bsum[threadIdx.x] = sm[threadIdx.x] - v;  // exclusive
}

__global__ void k_scan3(int* __restrict__ rp, const int* __restrict__ bsum, int n) {
  int i = blockIdx.x * 256 + threadIdx.x;
  if (i < n) rp[i + 1] += bsum[blockIdx.x];
  if (i == 0) rp[0] = 0;
}

__global__ void k_scatter(const int* __restrict__ src, const int* __restrict__ dst,
                          const int* __restrict__ rp, int* __restrict__ cur,
                          int* __restrict__ csr, int E) {
  int e = blockIdx.x * blockDim.x + threadIdx.x;
  if (e < E) {
    int d = dst[e];
    int pos = rp[d] + atomicAdd(&cur[d], 1);
    csr[pos] = src[e];
  }
}

// ---------------- prep: fp32 -> bf16 cast / fused weight transposes ----------------

__global__ void k_cast(const float* __restrict__ in, unsigned short* __restrict__ out, int n4) {
  int i = blockIdx.x * blockDim.x + threadIdx.x;
  if (i >= n4) return;
  float4 v = ((const float4*)in)[i];
  ushort4 o;
  o.x = f2bf(v.x);
  o.y = f2bf(v.y);
  o.z = f2bf(v.z);
  o.w = f2bf(v.w);
  ((ushort4*)out)[i] = o;
}

// All three weight transposes in one launch. W [K][Nc] fp32 -> Wt [NcPad][K] bf16.
__global__ void k_transW3(const float* __restrict__ W0, unsigned short* __restrict__ Wt0,
                          const float* __restrict__ W1, unsigned short* __restrict__ Wt1,
                          const float* __restrict__ W2, unsigned short* __restrict__ Wt2) {
  int i = blockIdx.x * blockDim.x + threadIdx.x;
  const int S0 = 256 * 256, S1 = 256 * 256, S2 = 128 * 256;
  if (i < S0) {
    int nc = i >> 8, k = i & 255;
    Wt0[i] = f2bf(W0[(size_t)k * 256 + nc]);
  } else if (i < S0 + S1) {
    int j = i - S0;
    int nc = j >> 8, k = j & 255;
    Wt1[j] = f2bf(W1[(size_t)k * 256 + nc]);
  } else if (i < S0 + S1 + S2) {
    int j = i - S0 - S1;
    int nc = j >> 8, k = j & 255;
    Wt2[j] = (nc < 40) ? f2bf(W2[(size_t)k * 40 + nc]) : (unsigned short)0;
  }
}

// ---------------- bf16 MFMA GEMM with fused attention projection epilogue ----------------
// C16[M,0:Nc] (row stride ldc) = A16 @ Bt^T; also a_s[row*heads+h] = sum_c C*asrc,
// a_d likewise, computed from fp32 accumulators. Head boundaries (64 cols) align with
// wave column blocks, so each (row, head) is produced by exactly one wave: no atomics.

__global__ __launch_bounds__(256) void k_mfma_gemm(
    const unsigned short* __restrict__ A, const unsigned short* __restrict__ Bt,
    unsigned short* __restrict__ C, const float* __restrict__ asrc,
    const float* __restrict__ adst, float* __restrict__ a_s, float* __restrict__ a_d, int M,
    int K, int Nc, int ldc, int heads, int acols) {
  constexpr int BM = 128, BK = 32, LDR = 40;
  __shared__ unsigned short As[BM * LDR];
  __shared__ unsigned short Bs[BM * LDR];
  int tid = threadIdx.x;
  int wave = tid >> 6, lane = tid & 63;
  int quad = lane >> 4, l16 = lane & 15;
  int wm = (wave & 1) * 64, wn = (wave >> 1) * 64;
  int bm = blockIdx.x * BM, bn = blockIdx.y * BM;
  f32x4 acc[4][4] = {};
  for (int k0 = 0; k0 < K; k0 += BK) {
#pragma unroll
    for (int it = 0; it < 2; it++) {
      int c = tid + it * 256;
      int row = c >> 2, part = c & 3;
      int gm = bm + row;
      ushortx8 va = (ushortx8)(0);
      if (gm < M) va = *(const ushortx8*)(A + (size_t)gm * K + k0 + part * 8);
      *(ushortx8*)(As + row * LDR + part * 8) = va;
      ushortx8 vb = *(const ushortx8*)(Bt + (size_t)(bn + row) * K + k0 + part * 8);
      *(ushortx8*)(Bs + row * LDR + part * 8) = vb;
    }
    __syncthreads();
    bf16x8 af[4], bf[4];
#pragma unroll
    for (int i = 0; i < 4; i++) {
      af[i] = *(const bf16x8*)(As + (wm + i * 16 + l16) * LDR + quad * 8);
      bf[i] = *(const bf16x8*)(Bs + (wn + i * 16 + l16) * LDR + quad * 8);
    }
#pragma unroll
    for (int i = 0; i < 4; i++)
#pragma unroll
      for (int j = 0; j < 4; j++)
        acc[i][j] = __builtin_amdgcn_mfma_f32_16x16x32_bf16(af[i], bf[j], acc[i][j], 0, 0, 0);
    __syncthreads();
  }
  // C write (bf16)
#pragma unroll
  for (int i = 0; i < 4; i++) {
#pragma unroll
    for (int j = 0; j < 4; j++) {
      int col = bn + wn + j * 16 + l16;
      if (col >= Nc) continue;
#pragma unroll
      for (int r = 0; r < 4; r++) {
        int row = bm + wm + i * 16 + quad * 4 + r;
        if (row < M) C[(size_t)row * ldc + col] = f2bf(acc[i][j][r]);
      }
    }
  }
  // fused attention projection epilogue
  int ghead = (bn + wn) >> 6;
  if (ghead < heads) {
    float asv[4], adv[4];
#pragma unroll
    for (int j = 0; j < 4; j++) {
      int col = bn + wn + j * 16 + l16;
      bool ok = col < acols;
      asv[j] = ok ? asrc[col] : 0.f;
      adv[j] = ok ? adst[col] : 0.f;
    }
#pragma unroll
    for (int i = 0; i < 4; i++) {
#pragma unroll
      for (int r = 0; r < 4; r++) {
        float s = acc[i][0][r] * asv[0] + acc[i][1][r] * asv[1] + acc[i][2][r] * asv[2] +
                  acc[i][3][r] * asv[3];
        float d = acc[i][0][r] * adv[0] + acc[i][1][r] * adv[1] + acc[i][2][r] * adv[2] +
                  acc[i][3][r] * adv[3];
#pragma unroll
        for (int mask = 1; mask <= 8; mask <<= 1) {
          s += __shfl_xor(s, mask, 64);
          d += __shfl_xor(d, mask, 64);
        }
        if (l16 == 0) {
          int row = bm + wm + i * 16 + quad * 4 + r;
          if (row < M) {
            a_s[row * heads + ghead] = s;
            a_d[row * heads + ghead] = d;
          }
        }
      }
    }
  }
}

// ---------------- fused softmax+aggregation: 2 waves per node, 4 edges lane-parallel ------
// Wave w of pair handles channels [ (w&1)*128, +128 ). Lane = quarter(q)*16 + l16;
// quarter q owns edge e+q, lanes cover 16x8=128 ch. psum is per-head by construction.

__global__ __launch_bounds__(256) void k_attn_agg256(
    const int* __restrict__ rp, const int* __restrict__ csr, const unsigned short* __restrict__ h,
    const float* __restrict__ a_s, const float* __restrict__ a_d, const float* __restrict__ bias,
    const float* __restrict__ bg, const float* __restrict__ bb, const float* __restrict__ bm,
    const float* __restrict__ bv, unsigned short* __restrict__ out, int n_nodes) {
  int wid = (blockIdx.x * blockDim.x + threadIdx.x) >> 6;
  int n = wid >> 1;
  if (n >= n_nodes) return;
  int chalf = (wid & 1) << 7;
  int lane = threadIdx.x & 63;
  int q = lane >> 4, l16 = lane & 15;
  int c = chalf + l16 * 8;
  int head = c >> 6;
  float ad = a_d[n * 4 + head];
  int beg = rp[n], end = rp[n + 1];
  float acc[8] = {};
  float psum = 0.f;
  int e = beg;
  for (; e + 8 <= end; e += 8) {
    int s0 = csr[e + q];
    int s1 = csr[e + 4 + q];
    float x0 = a_s[s0 * 4 + head] + ad;
    float x1 = a_s[s1 * 4 + head] + ad;
    ushortx8 v0 = *(const ushortx8*)(h + (size_t)s0 * 256 + c);
    ushortx8 v1 = *(const ushortx8*)(h + (size_t)s1 * 256 + c);
    x0 = x0 > 0.f ? x0 : x0 * kSlope;
    x1 = x1 > 0.f ? x1 : x1 * kSlope;
    float p0 = __expf(x0), p1 = __expf(x1);
    psum += p0 + p1;
#pragma unroll
    for (int j = 0; j < 8; j++) acc[j] += bf2f(v0[j]) * p0 + bf2f(v1[j]) * p1;
  }
  int rem = end - e;
  if (q < rem) {
    int s0 = csr[e + q];
    float x0 = a_s[s0 * 4 + head] + ad;
    x0 = x0 > 0.f ? x0 : x0 * kSlope;
    float p0 = __expf(x0);
    psum += p0;
    ushortx8 v0 = *(const ushortx8*)(h + (size_t)s0 * 256 + c);
#pragma unroll
    for (int j = 0; j < 8; j++) acc[j] += bf2f(v0[j]) * p0;
  }
  if (rem > 4 && q < rem - 4) {
    int s1 = csr[e + 4 + q];
    float x1 = a_s[s1 * 4 + head] + ad;
    x1 = x1 > 0.f ? x1 : x1 * kSlope;
    float p1 = __expf(x1);
    psum += p1;
    ushortx8 v1 = *(const ushortx8*)(h + (size_t)s1 * 256 + c);
#pragma unroll
    for (int j = 0; j < 8; j++) acc[j] += bf2f(v1[j]) * p1;
  }
  psum += __shfl_xor(psum, 16, 64);
  psum += __shfl_xor(psum, 32, 64);
#pragma unroll
  for (int j = 0; j < 8; j++) {
    acc[j] += __shfl_xor(acc[j], 16, 64);
    acc[j] += __shfl_xor(acc[j], 32, 64);
  }
  if (q == 0) {
    float rden = 1.f / (psum + 1e-16f);
    ushortx8 o;
#pragma unroll
    for (int j = 0; j < 8; j++) {
      float v = acc[j] * rden + bias[c + j];
      v = bg[c + j] * (v - bm[c + j]) * rsqrtf(bv[c + j] + kBnEps) + bb[c + j];
      v = v > 0.f ? v : (__expf(v) - 1.f);  // ELU
      o[j] = f2bf(v);
    }
    *(ushortx8*)(out + (size_t)n * 256 + c) = o;
  }
}

// ---------------- fused softmax+aggregation: wave per node, 40 ch (stride 64) ----------

__global__ __launch_bounds__(256) void k_attn_agg40(
    const int* __restrict__ rp, const int* __restrict__ csr, const unsigned short* __restrict__ h,
    const float* __restrict__ a_s, const float* __restrict__ a_d, const float* __restrict__ bias,
    float* __restrict__ out, int n_nodes) {
  int wid = (blockIdx.x * blockDim.x + threadIdx.x) >> 6;
  int lane = threadIdx.x & 63;
  if (wid >= n_nodes) return;
  int n = wid;
  int beg = rp[n], end = rp[n + 1];
  float ad = a_d[n];
  int grp = lane >> 3, l8 = lane & 7;
  int c = l8 * 8;
  float acc[8] = {};
  float psum = 0.f;
  for (int base = beg; base < end; base += 16) {
    int e0 = base + grp;
    int e1 = base + 8 + grp;
    if (e0 < end) {
      int s = csr[e0];
      float x = a_s[s] + ad;
      x = x > 0.f ? x : x * kSlope;
      float p = __expf(x);
      psum += p;
      ushortx8 hv = *(const ushortx8*)(h + (size_t)s * 64 + c);
#pragma unroll
      for (int j = 0; j < 8; j++) acc[j] += bf2f(hv[j]) * p;
    }
    if (e1 < end) {
      int s = csr[e1];
      float x = a_s[s] + ad;
      x = x > 0.f ? x : x * kSlope;
      float p = __expf(x);
      psum += p;
      ushortx8 hv = *(const ushortx8*)(h + (size_t)s * 64 + c);
#pragma unroll
      for (int j = 0; j < 8; j++) acc[j] += bf2f(hv[j]) * p;
    }
  }
#pragma unroll
  for (int mask = 8; mask <= 32; mask <<= 1) psum += __shfl_xor(psum, mask, 64);
#pragma unroll
  for (int j = 0; j < 8; j++) {
#pragma unroll
    for (int mask = 8; mask <= 32; mask <<= 1) acc[j] += __shfl_xor(acc[j], mask, 64);
  }
  if (lane < 5) {  // channels 0..39
    float rden = 1.f / (psum + 1e-16f);
    float4 o0, o1;
    o0.x = acc[0] * rden + bias[c + 0];
    o0.y = acc[1] * rden + bias[c + 1];
    o0.z = acc[2] * rden + bias[c + 2];
    o0.w = acc[3] * rden + bias[c + 3];
    o1.x = acc[4] * rden + bias[c + 4];
    o1.y = acc[5] * rden + bias[c + 5];
    o1.z = acc[6] * rden + bias[c + 6];
    o1.w = acc[7] * rden + bias[c + 7];
    *(float4*)(out + (size_t)n * 40 + c) = o0;
    *(float4*)(out + (size_t)n * 40 + c + 4) = o1;
  }
}

// ---------------- driver ----------------

extern "C" void kernel_launch(void* const* d_in, const int* in_sizes, int n_in, void* d_out,
                              int out_size, void* d_ws, size_t ws_size, hipStream_t stream) {
  const float* x = (const float*)d_in[0];
  const int* ei = (const int*)d_in[1];
  const float* W0 = (const float*)d_in[2];
  const float* as0 = (const float*)d_in[3];
  const float* ad0 = (const float*)d_in[4];
  const float* b0 = (const float*)d_in[5];
  const float* bg0 = (const float*)d_in[6];
  const float* bb0 = (const float*)d_in[7];
  const float* bm0 = (const float*)d_in[8];
  const float* bv0 = (const float*)d_in[9];
  const float* W1 = (const float*)d_in[10];
  const float* as1 = (const float*)d_in[11];
  const float* ad1 = (const float*)d_in[12];
  const float* b1 = (const float*)d_in[13];
  const float* bg1 = (const float*)d_in[14];
  const float* bb1 = (const float*)d_in[15];
  const float* bm1 = (const float*)d_in[16];
  const float* bv1 = (const float*)d_in[17];
  const float* W2 = (const float*)d_in[18];
  const float* as2 = (const float*)d_in[19];
  const float* ad2 = (const float*)d_in[20];
  const float* b2 = (const float*)d_in[21];
  float* out = (float*)d_out;

  const int E = in_sizes[1] / 2;
  const int* srcIdx = ei;
  const int* dstIdx = ei + E;

  char* p = (char*)d_ws;
  auto alloc = [&](size_t bytes) -> void* {
    void* r = (void*)p;
    p += (bytes + 255) & ~(size_t)255;
    return r;
  };
  int* rp = (int*)alloc((kN + 1) * sizeof(int));
  int* degcur = (int*)alloc((size_t)2 * kN * sizeof(int));  // deg | cursor
  int* deg = degcur;
  int* cur = degcur + kN;
  int* bsum = (int*)alloc(256 * sizeof(int));
  int* csr = (int*)alloc((size_t)E * sizeof(int));
  float* a_s = (float*)alloc((size_t)kN * 4 * sizeof(float));
  float* a_d = (float*)alloc((size_t)kN * 4 * sizeof(float));
  unsigned short* x16 = (unsigned short*)alloc((size_t)kN * 256 * 2);
  unsigned short* h16 = (unsigned short*)alloc((size_t)kN * 256 * 2);
  unsigned short* act16 = (unsigned short*)alloc((size_t)kN * 256 * 2);
  unsigned short* Wt0 = (unsigned short*)alloc((size_t)256 * 256 * 2);
  unsigned short* Wt1 = (unsigned short*)alloc((size_t)256 * 256 * 2);
  unsigned short* Wt2 = (unsigned short*)alloc((size_t)128 * 256 * 2);

  const int eb = ceil_div(E, 256);
  const int nb = ceil_div(kN, 256);

  // CSR build (edge_index identical for all layers)
  hipMemsetAsync(degcur, 0, (size_t)2 * kN * sizeof(int), stream);
  k_degree<<<eb, 256, 0, stream>>>(dstIdx, deg, E);
  k_scan1<<<nb, 256, 0, stream>>>(deg, rp, bsum, kN);
  k_scan2<<<1, 256, 0, stream>>>(bsum, nb);
  k_scan3<<<nb, 256, 0, stream>>>(rp, bsum, kN);
  k_scatter<<<eb, 256, 0, stream>>>(srcIdx, dstIdx, rp, cur, csr, E);

  // prep: cast + fused weight transposes
  k_cast<<<ceil_div(kN * 64, 256), 256, 0, stream>>>(x, x16, kN * 64);
  k_transW3<<<ceil_div(256 * 256 * 2 + 128 * 256, 256), 256, 0, stream>>>(W0, Wt0, W1, Wt1, W2,
                                                                          Wt2);

  dim3 gg(ceil_div(kN, 128), 2);
  dim3 gg2(ceil_div(kN, 128), 1);
  int agg256_blocks = ceil_div(2 * kN, 4);  // 2 waves/node, 4 waves/block
  int wpn_blocks = ceil_div(kN, 4);

  // Layer 0
  k_mfma_gemm<<<gg, 256, 0, stream>>>(x16, Wt0, h16, as0, ad0, a_s, a_d, kN, 256, 256, 256, 4,
                                      256);
  k_attn_agg256<<<agg256_blocks, 256, 0, stream>>>(rp, csr, h16, a_s, a_d, b0, bg0, bb0, bm0,
                                                   bv0, act16, kN);

  // Layer 1
  k_mfma_gemm<<<gg, 256, 0, stream>>>(act16, Wt1, h16, as1, ad1, a_s, a_d, kN, 256, 256, 256, 4,
                                      256);
  k_attn_agg256<<<agg256_blocks, 256, 0, stream>>>(rp, csr, h16, a_s, a_d, b1, bg1, bb1, bm1,
                                                   bv1, act16, kN);

  // Layer 2: h2 [N,40] stored with row stride 64 in h16
  k_mfma_gemm<<<gg2, 256, 0, stream>>>(act16, Wt2, h16, as2, ad2, a_s, a_d, kN, 256, 40, 64, 1,
                                       40);
  k_attn_agg40<<<wpn_blocks, 256, 0, stream>>>(rp, csr, h16, a_s, a_d, b2, out, kN);
}

// Round 8
// 455.674 us; speedup vs baseline: 1.0528x; 1.0528x over previous
//
#include <hip/hip_runtime.h>
#include <cstdint>
#include <cstddef>

constexpr int kN = 50000;
constexpr float kSlope = 0.2f;
constexpr float kBnEps = 1e-5f;

static inline int ceil_div(int a, int b) { return (a + b - 1) / b; }

typedef __attribute__((ext_vector_type(8))) _Float16 half8;
typedef __attribute__((ext_vector_type(8))) unsigned short ushortx8;
typedef __attribute__((ext_vector_type(4))) float f32x4;

__device__ inline unsigned short f2h_us(float f) {
  _Float16 h = (_Float16)f;
  return *(unsigned short*)&h;
}

// ---------------- CSR build ----------------

__global__ void k_degree(const int* __restrict__ dst, int* __restrict__ deg, int E) {
  int e = blockIdx.x * blockDim.x + threadIdx.x;
  if (e < E) atomicAdd(&deg[dst[e]], 1);
}

__global__ void k_scan1(const int* __restrict__ deg, int* __restrict__ rp,
                        int* __restrict__ bsum, int n) {
  __shared__ int sm[256];
  int i = blockIdx.x * 256 + threadIdx.x;
  int v = (i < n) ? deg[i] : 0;
  sm[threadIdx.x] = v;
  __syncthreads();
  for (int off = 1; off < 256; off <<= 1) {
    int t = (threadIdx.x >= off) ? sm[threadIdx.x - off] : 0;
    __syncthreads();
    sm[threadIdx.x] += t;
    __syncthreads();
  }
  if (i < n) rp[i + 1] = sm[threadIdx.x];
  if (threadIdx.x == 255) bsum[blockIdx.x] = sm[255];
}

__global__ void k_scan2(int* bsum, int nb) {
  __shared__ int sm[256];
  int v = (threadIdx.x < nb) ? bsum[threadIdx.x] : 0;
  sm[threadIdx.x] = v;
  __syncthreads();
  for (int off = 1; off < 256; off <<= 1) {
    int t = (threadIdx.x >= off) ? sm[threadIdx.x - off] : 0;
    __syncthreads();
    sm[threadIdx.x] += t;
    __syncthreads();
  }
  if (threadIdx.x < nb) bsum[threadIdx.x] = sm[threadIdx.x] - v;  // exclusive
}

__global__ void k_scan3(int* __restrict__ rp, const int* __restrict__ bsum, int n) {
  int i = blockIdx.x * 256 + threadIdx.x;
  if (i < n) rp[i + 1] += bsum[blockIdx.x];
  if (i == 0) rp[0] = 0;
}

__global__ void k_scatter(const int* __restrict__ src, const int* __restrict__ dst,
                          const int* __restrict__ rp, int* __restrict__ cur,
                          int* __restrict__ csr, int E) {
  int e = blockIdx.x * blockDim.x + threadIdx.x;
  if (e < E) {
    int d = dst[e];
    int pos = rp[d] + atomicAdd(&cur[d], 1);
    csr[pos] = src[e];
  }
}

// ---------------- prep: fp32 -> f16 cast / fused weight transposes ----------------

__global__ void k_cast(const float* __restrict__ in, unsigned short* __restrict__ out, int n4) {
  int i = blockIdx.x * blockDim.x + threadIdx.x;
  if (i >= n4) return;
  float4 v = ((const float4*)in)[i];
  ushort4 o;
  o.x = f2h_us(v.x);
  o.y = f2h_us(v.y);
  o.z = f2h_us(v.z);
  o.w = f2h_us(v.w);
  ((ushort4*)out)[i] = o;
}

// All three weight transposes in one launch. W [K][Nc] fp32 -> Wt [NcPad][K] f16.
__global__ void k_transW3(const float* __restrict__ W0, unsigned short* __restrict__ Wt0,
                          const float* __restrict__ W1, unsigned short* __restrict__ Wt1,
                          const float* __restrict__ W2, unsigned short* __restrict__ Wt2) {
  int i = blockIdx.x * blockDim.x + threadIdx.x;
  const int S0 = 256 * 256, S1 = 256 * 256, S2 = 128 * 256;
  if (i < S0) {
    int nc = i >> 8, k = i & 255;
    Wt0[i] = f2h_us(W0[(size_t)k * 256 + nc]);
  } else if (i < S0 + S1) {
    int j = i - S0;
    int nc = j >> 8, k = j & 255;
    Wt1[j] = f2h_us(W1[(size_t)k * 256 + nc]);
  } else if (i < S0 + S1 + S2) {
    int j = i - S0 - S1;
    int nc = j >> 8, k = j & 255;
    Wt2[j] = (nc < 40) ? f2h_us(W2[(size_t)k * 40 + nc]) : (unsigned short)0;
  }
}

// ---------------- f16 MFMA GEMM with fused attention projection epilogue ----------------

__global__ __launch_bounds__(256) void k_mfma_gemm(
    const unsigned short* __restrict__ A, const unsigned short* __restrict__ Bt,
    unsigned short* __restrict__ C, const float* __restrict__ asrc,
    const float* __restrict__ adst, float* __restrict__ a_s, float* __restrict__ a_d, int M,
    int K, int Nc, int ldc, int heads, int acols) {
  constexpr int BM = 128, BK = 32, LDR = 40;
  __shared__ unsigned short As[BM * LDR];
  __shared__ unsigned short Bs[BM * LDR];
  int tid = threadIdx.x;
  int wave = tid >> 6, lane = tid & 63;
  int quad = lane >> 4, l16 = lane & 15;
  int wm = (wave & 1) * 64, wn = (wave >> 1) * 64;
  int bm = blockIdx.x * BM, bn = blockIdx.y * BM;
  f32x4 acc[4][4] = {};
  for (int k0 = 0; k0 < K; k0 += BK) {
#pragma unroll
    for (int it = 0; it < 2; it++) {
      int c = tid + it * 256;
      int row = c >> 2, part = c & 3;
      int gm = bm + row;
      ushortx8 va = (ushortx8)(0);
      if (gm < M) va = *(const ushortx8*)(A + (size_t)gm * K + k0 + part * 8);
      *(ushortx8*)(As + row * LDR + part * 8) = va;
      ushortx8 vb = *(const ushortx8*)(Bt + (size_t)(bn + row) * K + k0 + part * 8);
      *(ushortx8*)(Bs + row * LDR + part * 8) = vb;
    }
    __syncthreads();
    half8 af[4], bf[4];
#pragma unroll
    for (int i = 0; i < 4; i++) {
      af[i] = *(const half8*)(As + (wm + i * 16 + l16) * LDR + quad * 8);
      bf[i] = *(const half8*)(Bs + (wn + i * 16 + l16) * LDR + quad * 8);
    }
#pragma unroll
    for (int i = 0; i < 4; i++)
#pragma unroll
      for (int j = 0; j < 4; j++)
        acc[i][j] = __builtin_amdgcn_mfma_f32_16x16x32_f16(af[i], bf[j], acc[i][j], 0, 0, 0);
    __syncthreads();
  }
  // C write (f16)
#pragma unroll
  for (int i = 0; i < 4; i++) {
#pragma unroll
    for (int j = 0; j < 4; j++) {
      int col = bn + wn + j * 16 + l16;
      if (col >= Nc) continue;
#pragma unroll
      for (int r = 0; r < 4; r++) {
        int row = bm + wm + i * 16 + quad * 4 + r;
        if (row < M) C[(size_t)row * ldc + col] = f2h_us(acc[i][j][r]);
      }
    }
  }
  // fused attention projection epilogue
  int ghead = (bn + wn) >> 6;
  if (ghead < heads) {
    float asv[4], adv[4];
#pragma unroll
    for (int j = 0; j < 4; j++) {
      int col = bn + wn + j * 16 + l16;
      bool ok = col < acols;
      asv[j] = ok ? asrc[col] : 0.f;
      adv[j] = ok ? adst[col] : 0.f;
    }
#pragma unroll
    for (int i = 0; i < 4; i++) {
#pragma unroll
      for (int r = 0; r < 4; r++) {
        float s = acc[i][0][r] * asv[0] + acc[i][1][r] * asv[1] + acc[i][2][r] * asv[2] +
                  acc[i][3][r] * asv[3];
        float d = acc[i][0][r] * adv[0] + acc[i][1][r] * adv[1] + acc[i][2][r] * adv[2] +
                  acc[i][3][r] * adv[3];
#pragma unroll
        for (int mask = 1; mask <= 8; mask <<= 1) {
          s += __shfl_xor(s, mask, 64);
          d += __shfl_xor(d, mask, 64);
        }
        if (l16 == 0) {
          int row = bm + wm + i * 16 + quad * 4 + r;
          if (row < M) {
            a_s[row * heads + ghead] = s;
            a_d[row * heads + ghead] = d;
          }
        }
      }
    }
  }
}

// ---------------- fused softmax+aggregation: wave per node, 256 ch, f16 h ----------------
// R6 layout (best measured): halves own alternating edges, 8 ch/lane, fma_mix inner loop.

__global__ __launch_bounds__(256) void k_attn_agg256(
    const int* __restrict__ rp, const int* __restrict__ csr, const _Float16* __restrict__ h,
    const float* __restrict__ a_s, const float* __restrict__ a_d, const float* __restrict__ bias,
    const float* __restrict__ bg, const float* __restrict__ bb, const float* __restrict__ bm,
    const float* __restrict__ bv, unsigned short* __restrict__ out, int n_nodes) {
  int wid = (blockIdx.x * blockDim.x + threadIdx.x) >> 6;
  int lane = threadIdx.x & 63;
  if (wid >= n_nodes) return;
  int n = wid;
  int beg = rp[n], end = rp[n + 1];
  int half = lane >> 5, l32 = lane & 31;
  int head = l32 >> 3;  // 8 lanes x 8 ch per head
  int c = l32 * 8;
  float ad = a_d[n * 4 + head];
  float acc[8] = {};
  float psum = 0.f;
  int e = beg;
  for (; e + 8 <= end; e += 8) {
    int s0 = csr[e + half];
    int s1 = csr[e + 2 + half];
    int s2 = csr[e + 4 + half];
    int s3 = csr[e + 6 + half];
    float x0 = a_s[s0 * 4 + head] + ad;
    float x1 = a_s[s1 * 4 + head] + ad;
    float x2 = a_s[s2 * 4 + head] + ad;
    float x3 = a_s[s3 * 4 + head] + ad;
    half8 v0 = *(const half8*)(h + (size_t)s0 * 256 + c);
    half8 v1 = *(const half8*)(h + (size_t)s1 * 256 + c);
    half8 v2 = *(const half8*)(h + (size_t)s2 * 256 + c);
    half8 v3 = *(const half8*)(h + (size_t)s3 * 256 + c);
    x0 = x0 > 0.f ? x0 : x0 * kSlope;
    x1 = x1 > 0.f ? x1 : x1 * kSlope;
    x2 = x2 > 0.f ? x2 : x2 * kSlope;
    x3 = x3 > 0.f ? x3 : x3 * kSlope;
    float p0 = __expf(x0), p1 = __expf(x1);
    float p2 = __expf(x2), p3 = __expf(x3);
    psum += (p0 + p1) + (p2 + p3);
#pragma unroll
    for (int j = 0; j < 8; j++) {
      acc[j] += (float)v0[j] * p0 + (float)v1[j] * p1;
      acc[j] += (float)v2[j] * p2 + (float)v3[j] * p3;
    }
  }
  for (; e + 2 <= end; e += 2) {
    int s0 = csr[e + half];
    float x0 = a_s[s0 * 4 + head] + ad;
    x0 = x0 > 0.f ? x0 : x0 * kSlope;
    float p0 = __expf(x0);
    psum += p0;
    half8 v0 = *(const half8*)(h + (size_t)s0 * 256 + c);
#pragma unroll
    for (int j = 0; j < 8; j++) acc[j] += (float)v0[j] * p0;
  }
  if (e < end && half == 0) {
    int s0 = csr[e];
    float x0 = a_s[s0 * 4 + head] + ad;
    x0 = x0 > 0.f ? x0 : x0 * kSlope;
    float p0 = __expf(x0);
    psum += p0;
    half8 v0 = *(const half8*)(h + (size_t)s0 * 256 + c);
#pragma unroll
    for (int j = 0; j < 8; j++) acc[j] += (float)v0[j] * p0;
  }
  psum += __shfl_xor(psum, 32, 64);
#pragma unroll
  for (int j = 0; j < 8; j++) acc[j] += __shfl_xor(acc[j], 32, 64);
  if (half == 0) {
    float rden = 1.f / (psum + 1e-16f);
    ushortx8 o;
#pragma unroll
    for (int j = 0; j < 8; j++) {
      float v = acc[j] * rden + bias[c + j];
      v = bg[c + j] * (v - bm[c + j]) * rsqrtf(bv[c + j] + kBnEps) + bb[c + j];
      v = v > 0.f ? v : (__expf(v) - 1.f);  // ELU
      o[j] = f2h_us(v);
    }
    *(ushortx8*)(out + (size_t)n * 256 + c) = o;
  }
}

// ---------------- fused softmax+aggregation: wave per node, 40 ch (stride 64) ----------

__global__ __launch_bounds__(256) void k_attn_agg40(
    const int* __restrict__ rp, const int* __restrict__ csr, const _Float16* __restrict__ h,
    const float* __restrict__ a_s, const float* __restrict__ a_d, const float* __restrict__ bias,
    float* __restrict__ out, int n_nodes) {
  int wid = (blockIdx.x * blockDim.x + threadIdx.x) >> 6;
  int lane = threadIdx.x & 63;
  if (wid >= n_nodes) return;
  int n = wid;
  int beg = rp[n], end = rp[n + 1];
  float ad = a_d[n];
  int grp = lane >> 3, l8 = lane & 7;
  int c = l8 * 8;
  float acc[8] = {};
  float psum = 0.f;
  for (int base = beg; base < end; base += 16) {
    int e0 = base + grp;
    int e1 = base + 8 + grp;
    if (e0 < end) {
      int s = csr[e0];
      float x = a_s[s] + ad;
      x = x > 0.f ? x : x * kSlope;
      float p = __expf(x);
      psum += p;
      half8 hv = *(const half8*)(h + (size_t)s * 64 + c);
#pragma unroll
      for (int j = 0; j < 8; j++) acc[j] += (float)hv[j] * p;
    }
    if (e1 < end) {
      int s = csr[e1];
      float x = a_s[s] + ad;
      x = x > 0.f ? x : x * kSlope;
      float p = __expf(x);
      psum += p;
      half8 hv = *(const half8*)(h + (size_t)s * 64 + c);
#pragma unroll
      for (int j = 0; j < 8; j++) acc[j] += (float)hv[j] * p;
    }
  }
#pragma unroll
  for (int mask = 8; mask <= 32; mask <<= 1) psum += __shfl_xor(psum, mask, 64);
#pragma unroll
  for (int j = 0; j < 8; j++) {
#pragma unroll
    for (int mask = 8; mask <= 32; mask <<= 1) acc[j] += __shfl_xor(acc[j], mask, 64);
  }
  if (lane < 5) {  // channels 0..39
    float rden = 1.f / (psum + 1e-16f);
    float4 o0, o1;
    o0.x = acc[0] * rden + bias[c + 0];
    o0.y = acc[1] * rden + bias[c + 1];
    o0.z = acc[2] * rden + bias[c + 2];
    o0.w = acc[3] * rden + bias[c + 3];
    o1.x = acc[4] * rden + bias[c + 4];
    o1.y = acc[5] * rden + bias[c + 5];
    o1.z = acc[6] * rden + bias[c + 6];
    o1.w = acc[7] * rden + bias[c + 7];
    *(float4*)(out + (size_t)n * 40 + c) = o0;
    *(float4*)(out + (size_t)n * 40 + c + 4) = o1;
  }
}

// ---------------- driver ----------------

extern "C" void kernel_launch(void* const* d_in, const int* in_sizes, int n_in, void* d_out,
                              int out_size, void* d_ws, size_t ws_size, hipStream_t stream) {
  const float* x = (const float*)d_in[0];
  const int* ei = (const int*)d_in[1];
  const float* W0 = (const float*)d_in[2];
  const float* as0 = (const float*)d_in[3];
  const float* ad0 = (const float*)d_in[4];
  const float* b0 = (const float*)d_in[5];
  const float* bg0 = (const float*)d_in[6];
  const float* bb0 = (const float*)d_in[7];
  const float* bm0 = (const float*)d_in[8];
  const float* bv0 = (const float*)d_in[9];
  const float* W1 = (const float*)d_in[10];
  const float* as1 = (const float*)d_in[11];
  const float* ad1 = (const float*)d_in[12];
  const float* b1 = (const float*)d_in[13];
  const float* bg1 = (const float*)d_in[14];
  const float* bb1 = (const float*)d_in[15];
  const float* bm1 = (const float*)d_in[16];
  const float* bv1 = (const float*)d_in[17];
  const float* W2 = (const float*)d_in[18];
  const float* as2 = (const float*)d_in[19];
  const float* ad2 = (const float*)d_in[20];
  const float* b2 = (const float*)d_in[21];
  float* out = (float*)d_out;

  const int E = in_sizes[1] / 2;
  const int* srcIdx = ei;
  const int* dstIdx = ei + E;

  char* p = (char*)d_ws;
  auto alloc = [&](size_t bytes) -> void* {
    void* r = (void*)p;
    p += (bytes + 255) & ~(size_t)255;
    return r;
  };
  int* rp = (int*)alloc((kN + 1) * sizeof(int));
  int* degcur = (int*)alloc((size_t)2 * kN * sizeof(int));  // deg | cursor
  int* deg = degcur;
  int* cur = degcur + kN;
  int* bsum = (int*)alloc(256 * sizeof(int));
  int* csr = (int*)alloc((size_t)E * sizeof(int));
  float* a_s = (float*)alloc((size_t)kN * 4 * sizeof(float));
  float* a_d = (float*)alloc((size_t)kN * 4 * sizeof(float));
  unsigned short* x16 = (unsigned short*)alloc((size_t)kN * 256 * 2);
  unsigned short* h16 = (unsigned short*)alloc((size_t)kN * 256 * 2);
  unsigned short* act16 = (unsigned short*)alloc((size_t)kN * 256 * 2);
  unsigned short* Wt0 = (unsigned short*)alloc((size_t)256 * 256 * 2);
  unsigned short* Wt1 = (unsigned short*)alloc((size_t)256 * 256 * 2);
  unsigned short* Wt2 = (unsigned short*)alloc((size_t)128 * 256 * 2);

  const int eb = ceil_div(E, 256);
  const int nb = ceil_div(kN, 256);

  // CSR build (edge_index identical for all layers)
  hipMemsetAsync(degcur, 0, (size_t)2 * kN * sizeof(int), stream);
  k_degree<<<eb, 256, 0, stream>>>(dstIdx, deg, E);
  k_scan1<<<nb, 256, 0, stream>>>(deg, rp, bsum, kN);
  k_scan2<<<1, 256, 0, stream>>>(bsum, nb);
  k_scan3<<<nb, 256, 0, stream>>>(rp, bsum, kN);
  k_scatter<<<eb, 256, 0, stream>>>(srcIdx, dstIdx, rp, cur, csr, E);

  // prep: cast + fused weight transposes
  k_cast<<<ceil_div(kN * 64, 256), 256, 0, stream>>>(x, x16, kN * 64);
  k_transW3<<<ceil_div(256 * 256 * 2 + 128 * 256, 256), 256, 0, stream>>>(W0, Wt0, W1, Wt1, W2,
                                                                          Wt2);

  dim3 gg(ceil_div(kN, 128), 2);
  dim3 gg2(ceil_div(kN, 128), 1);
  int wpn_blocks = ceil_div(kN, 4);  // wave-per-node kernels

  // Layer 0
  k_mfma_gemm<<<gg, 256, 0, stream>>>(x16, Wt0, h16, as0, ad0, a_s, a_d, kN, 256, 256, 256, 4,
                                      256);
  k_attn_agg256<<<wpn_blocks, 256, 0, stream>>>(rp, csr, (const _Float16*)h16, a_s, a_d, b0, bg0,
                                                bb0, bm0, bv0, act16, kN);

  // Layer 1
  k_mfma_gemm<<<gg, 256, 0, stream>>>(act16, Wt1, h16, as1, ad1, a_s, a_d, kN, 256, 256, 256, 4,
                                      256);
  k_attn_agg256<<<wpn_blocks, 256, 0, stream>>>(rp, csr, (const _Float16*)h16, a_s, a_d, b1, bg1,
                                                bb1, bm1, bv1, act16, kN);

  // Layer 2: h2 [N,40] stored with row stride 64 in h16
  k_mfma_gemm<<<gg2, 256, 0, stream>>>(act16, Wt2, h16, as2, ad2, a_s, a_d, kN, 256, 40, 64, 1,
                                       40);
  k_attn_agg40<<<wpn_blocks, 256, 0, stream>>>(rp, csr, (const _Float16*)h16, a_s, a_d, b2, out,
                                               kN);
}